// Round 9
// baseline (248.341 us; speedup 1.0000x reference)
//
#include <hip/hip_runtime.h>

#define GS 128
#define GS3 (GS*GS*GS)
#define NPTS 150000
#define NBATCH 2
#define BN_TOT (NBATCH*NPTS)       // 300000
#define CONV_BLOCKS 1172           // 256 rows/block (4 waves x 64 rows)
#define BN_PAD (CONV_BLOCKS*256)   // 300032
#define ZROW   BN_PAD              // zero feature row index
#define EPS 1e-5f
#define NBKT 8192                  // 2 batches * 16^3 coarse buckets

// ws layout (~61 MB)
#define OFF_GRID   0ull
#define SZ_GRID    ((size_t)NBATCH*GS3*4)            // 16,777,216
#define OFF_WFRAG  (OFF_GRID + SZ_GRID)
#define SZ_WFRAG   ((size_t)27*4096*2)               // 221,184
#define OFF_STATS  (OFF_WFRAG + SZ_WFRAG)            // 512
#define OFF_CNT    (OFF_STATS + 512)                 // 32,768
#define OFF_CUR    (OFF_CNT + NBKT*4)                // 32,768
#define OFF_SIDX   (OFF_CUR + NBKT*4)                // 1,200,128
#define OFF_CSORT  (OFF_SIDX + 1200128)              // BN_PAD*16
#define OFF_FB16S  (OFF_CSORT + (size_t)BN_PAD*16)   // (BN_PAD+1)*128

typedef __attribute__((ext_vector_type(8))) short bf16x8;
typedef __attribute__((ext_vector_type(4))) float f32x4;
typedef unsigned int u32;

__device__ __forceinline__ short f2bf(float f) {
    union { float f; unsigned u; } v; v.f = f;
    unsigned rr = v.u + 0x7fffu + ((v.u >> 16) & 1u);   // RNE
    return (short)(rr >> 16);
}

// ---------- kernel 1: grid scatter (max orig pid) + bucket histogram ----------
__global__ __launch_bounds__(256) void k_count(const int* __restrict__ coords,
                                               int* __restrict__ grid,
                                               u32* __restrict__ cnt) {
    int p = blockIdx.x*256 + threadIdx.x;
    if (p >= BN_TOT) return;
    int x = coords[p*3+0], y = coords[p*3+1], z = coords[p*3+2];
    int b = (p >= NPTS);
    atomicMax(&grid[(b<<21) | (x<<14) | (y<<7) | z], p);
    atomicAdd(&cnt[(b<<12) | ((x>>3)<<8) | ((y>>3)<<4) | (z>>3)], 1u);
}

// ---------- kernel 2: exclusive scan of 8192 bucket counts ----------
__global__ __launch_bounds__(1024) void k_scan(const u32* __restrict__ cnt,
                                               u32* __restrict__ cur) {
    __shared__ u32 ps[1024];
    int t = threadIdx.x;
    u32 l[8]; u32 s = 0;
    #pragma unroll
    for (int i = 0; i < 8; ++i) { l[i] = cnt[t*8+i]; s += l[i]; }
    ps[t] = s; __syncthreads();
    for (int off = 1; off < 1024; off <<= 1) {
        u32 v = (t >= off) ? ps[t-off] : 0u; __syncthreads();
        ps[t] += v; __syncthreads();
    }
    u32 run = (t == 0) ? 0u : ps[t-1];
    #pragma unroll
    for (int i = 0; i < 8; ++i) { cur[t*8+i] = run; run += l[i]; }
}

// ---------- kernel 3: place points in bucket order + bf16 features ----------
__global__ __launch_bounds__(256) void k_place(const float* __restrict__ feats,
                                               const int* __restrict__ coords,
                                               u32* __restrict__ cur,
                                               int* __restrict__ sortidx,
                                               int4* __restrict__ csorted,
                                               ushort* __restrict__ fb16s) {
    int p = blockIdx.x*256 + threadIdx.x;
    if (p >= BN_PAD) return;
    if (p >= BN_TOT) { csorted[p] = make_int4(-9,-9,-9,0); return; }
    int x = coords[p*3+0], y = coords[p*3+1], z = coords[p*3+2];
    int b = (p >= NPTS);
    int bkt = (b<<12) | ((x>>3)<<8) | ((y>>3)<<4) | (z>>3);
    int pos = (int)atomicAdd(&cur[bkt], 1u);
    sortidx[p] = pos;
    csorted[pos] = make_int4(x, y, z, p);
    const float4* s = (const float4*)(feats + (size_t)p*64);
    ushort* d = fb16s + (size_t)pos*64;
    #pragma unroll
    for (int i = 0; i < 8; ++i) {
        float4 a = s[2*i], c = s[2*i+1];
        ushort4 u0 = { (ushort)f2bf(a.x),(ushort)f2bf(a.y),(ushort)f2bf(a.z),(ushort)f2bf(a.w) };
        ushort4 u1 = { (ushort)f2bf(c.x),(ushort)f2bf(c.y),(ushort)f2bf(c.z),(ushort)f2bf(c.w) };
        ((ushort4*)d)[2*i] = u0; ((ushort4*)d)[2*i+1] = u1;
    }
}

// ---------- kernel 4: weight -> bf16 MFMA B-fragments ----------
__global__ __launch_bounds__(256) void k_prefrag(const float* __restrict__ w,
                                                 short* __restrict__ wfrag) {
    int t = blockIdx.x * 256 + threadIdx.x;
    if (t >= 27*4096) return;
    int i    = t & 7;
    int lane = (t >> 3) & 63;
    int tt   = (t >> 9) & 3;
    int c    = (t >> 11) & 1;
    int k    = t >> 12;
    int kk = c*32 + (lane >> 4)*8 + i;
    int co = tt*16 + (lane & 15);
    wfrag[t] = f2bf(w[(k*64 + kk)*64 + co]);
}

// ---------- kernel 5: barrier-free wave-autonomous MFMA conv ----------
// 4 waves/block, wave = 64 sorted rows (4 tiles) x 64 cout. Block builds its
// 27x256 rulebook into LDS once; main loop has NO barriers and NO LDS staging:
// both A (gathered rows) and B (L2-hot wfrag, coalesced) are register-
// prefetched 2 phases deep. Phase k: vmcnt(16) [drains B(k)+A(k), keeps
// B(k+1)+A(k+1) flying], 32 MFMA (setprio), issue B(k+2)+A(k+2).
__global__ __launch_bounds__(256) void k_conv(
    const ushort* __restrict__ fb16s,
    const int4* __restrict__ csorted,
    const int* __restrict__ grid,
    const int* __restrict__ sortidx,
    const ushort* __restrict__ wfrag,
    float* __restrict__ out,
    float* __restrict__ gstats)
{
    __shared__ int ids_lds[27*256];                  // 27.6KB block rulebook
    __shared__ float bsum[64], bsq[64];

    const int tid  = threadIdx.x;
    const int lane = tid & 63;
    const int wv   = tid >> 6;
    const int r    = lane & 15;
    const int seg  = lane >> 4;
    const int p0b  = blockIdx.x * 256;
    const int rbase = wv*64 + r;                     // + t*16 per tile

    // ---- prologue A: inline rulebook (27 probes + sortidx per thread) ----
    {
        int4 c = csorted[p0b + tid];
        const bool pad = (p0b + tid >= BN_TOT);
        const int gb = (c.w >= NPTS) ? GS3 : 0;
        #pragma unroll
        for (int k = 0; k < 27; ++k) {
            int dx = k/9 - 1, dy = (k/3)%3 - 1, dz = k%3 - 1;   // compile-time
            int nx = c.x+dx, ny = c.y+dy, nz = c.z+dz;
            int ok = (int)(!pad & ((unsigned)nx < 128u) & ((unsigned)ny < 128u) &
                           ((unsigned)nz < 128u));
            int pid = grid[gb + ((nx&127)<<14) + ((ny&127)<<7) + (nz&127)];
            pid = ok ? pid : -1;
            int sv = sortidx[pid < 0 ? 0 : pid];
            ids_lds[k*256 + tid] = (pid >= 0) ? sv : ZROW;
        }
    }
    if (tid < 64) { bsum[tid] = 0.f; bsq[tid] = 0.f; }
    __syncthreads();                                 // rulebook ready, vmem drained

#define LDA16(AC, S) { _Pragma("unroll") for (int t_ = 0; t_ < 4; ++t_) {     \
        const ushort* ap_ = fb16s + (size_t)(S)[t_]*64 + seg*8;               \
        AC[2*t_]   = *(const bf16x8*)(ap_);                                   \
        AC[2*t_+1] = *(const bf16x8*)(ap_ + 32); } }
#define LDB8(BC, kk) { const bf16x8* wp_ = (const bf16x8*)wfrag + (size_t)(kk)*512; \
        _Pragma("unroll") for (int f_ = 0; f_ < 8; ++f_) BC[f_] = wp_[f_*64 + lane]; }
#define LDIDS(S, kk) { _Pragma("unroll") for (int t_ = 0; t_ < 4; ++t_)       \
        S[t_] = ids_lds[(kk)*256 + rbase + t_*16]; }

    f32x4 acc[4][4];
    #pragma unroll
    for (int t = 0; t < 4; ++t)
        #pragma unroll
        for (int q = 0; q < 4; ++q) acc[t][q] = (f32x4){0,0,0,0};

    bf16x8 aE[8], aO[8], bE[8], bO[8];
    int sE[4], sO[4];

    // ---- prologue B: fill pipeline (issue order B(0) A(0) B(1) A(1)) ----
    LDIDS(sE, 0); LDIDS(sO, 1);
    __builtin_amdgcn_sched_barrier(0);
    LDB8(bE, 0);
    LDA16(aE, sE);
    __builtin_amdgcn_sched_barrier(0);
    LDB8(bO, 1);
    LDA16(aO, sO);
    __builtin_amdgcn_sched_barrier(0);
    // invariant entering phase k: outstanding = [B(k)8, A(k)8, B(k+1)8, A(k+1)8]

    auto phase = [&](int k, bf16x8 (&AC)[8], bf16x8 (&BC)[8]) {
        int kp2 = (k+2 > 26) ? 26 : k+2;
        int sn[4]; LDIDS(sn, kp2);                   // lgkm; hides under MFMAs
        asm volatile("s_waitcnt vmcnt(16)" ::: "memory");
        __builtin_amdgcn_sched_barrier(0);
        __builtin_amdgcn_s_setprio(1);
        #pragma unroll
        for (int t = 0; t < 4; ++t) {
            acc[t][0] = __builtin_amdgcn_mfma_f32_16x16x32_bf16(AC[2*t], BC[0], acc[t][0], 0,0,0);
            acc[t][1] = __builtin_amdgcn_mfma_f32_16x16x32_bf16(AC[2*t], BC[1], acc[t][1], 0,0,0);
            acc[t][2] = __builtin_amdgcn_mfma_f32_16x16x32_bf16(AC[2*t], BC[2], acc[t][2], 0,0,0);
            acc[t][3] = __builtin_amdgcn_mfma_f32_16x16x32_bf16(AC[2*t], BC[3], acc[t][3], 0,0,0);
            acc[t][0] = __builtin_amdgcn_mfma_f32_16x16x32_bf16(AC[2*t+1], BC[4], acc[t][0], 0,0,0);
            acc[t][1] = __builtin_amdgcn_mfma_f32_16x16x32_bf16(AC[2*t+1], BC[5], acc[t][1], 0,0,0);
            acc[t][2] = __builtin_amdgcn_mfma_f32_16x16x32_bf16(AC[2*t+1], BC[6], acc[t][2], 0,0,0);
            acc[t][3] = __builtin_amdgcn_mfma_f32_16x16x32_bf16(AC[2*t+1], BC[7], acc[t][3], 0,0,0);
        }
        __builtin_amdgcn_s_setprio(0);
        __builtin_amdgcn_sched_barrier(0);
        LDB8(BC, kp2);                               // B(k+2) into freed regs
        LDA16(AC, sn);                               // A(k+2) into freed regs
        __builtin_amdgcn_sched_barrier(0);
    };

    #pragma unroll 1
    for (int t = 0; t < 13; ++t) {
        phase(2*t,   aE, bE);
        phase(2*t+1, aO, bO);
    }
    phase(26, aE, bE);

    // ---- epilogue: scatter to out[orig pid]; C/D col=lane&15, row=seg*4+j ----
    #pragma unroll
    for (int t = 0; t < 4; ++t) {
        #pragma unroll
        for (int j = 0; j < 4; ++j) {
            int row = p0b + wv*64 + t*16 + seg*4 + j;
            if (row < BN_TOT) {
                int opid = csorted[row].w;
                float* ob = out + (size_t)opid*64 + r;
                ob[ 0] = acc[t][0][j];
                ob[16] = acc[t][1][j];
                ob[32] = acc[t][2][j];
                ob[48] = acc[t][3][j];
            }
        }
    }

    // ---- fused stats (pad rows contribute exact zeros) ----
    float s_[4] = {0,0,0,0}, q_[4] = {0,0,0,0};
    #pragma unroll
    for (int q = 0; q < 4; ++q)
        #pragma unroll
        for (int t = 0; t < 4; ++t)
            #pragma unroll
            for (int j = 0; j < 4; ++j) {
                float v = acc[t][q][j]; s_[q] += v; q_[q] += v*v;
            }
    #pragma unroll
    for (int q = 0; q < 4; ++q) {
        atomicAdd(&bsum[q*16 + r], s_[q]);
        atomicAdd(&bsq [q*16 + r], q_[q]);
    }
    __syncthreads();
    if (tid < 64) { atomicAdd(&gstats[tid], bsum[tid]); atomicAdd(&gstats[64+tid], bsq[tid]); }
#undef LDA16
#undef LDB8
#undef LDIDS
}

// ---------- kernel 6: normalize + affine + ReLU, in place ----------
__global__ __launch_bounds__(256) void k_norm(float* __restrict__ out,
                                              const float* __restrict__ stats,
                                              const float* __restrict__ gamma,
                                              const float* __restrict__ beta) {
    int i = blockIdx.x*256 + threadIdx.x;
    const int n4 = BN_TOT*16;
    if (i >= n4) return;
    float4 v = ((const float4*)out)[i];
    int ch = (i & 15) * 4;
    float o[4] = {v.x, v.y, v.z, v.w};
    float rp[4];
    #pragma unroll
    for (int j = 0; j < 4; ++j) {
        int c = ch + j;
        float mean = stats[c] * (1.f/BN_TOT);
        float var  = stats[64+c] * (1.f/BN_TOT) - mean*mean;
        float y = (o[j] - mean) * rsqrtf(var + EPS) * gamma[c] + beta[c];
        rp[j] = fmaxf(y, 0.f);
    }
    float4 rv; rv.x = rp[0]; rv.y = rp[1]; rv.z = rp[2]; rv.w = rp[3];
    ((float4*)out)[i] = rv;
}

extern "C" void kernel_launch(void* const* d_in, const int* in_sizes, int n_in,
                              void* d_out, int out_size, void* d_ws, size_t ws_size,
                              hipStream_t stream) {
    const float* feats  = (const float*)d_in[0];
    const int*   coords = (const int*)d_in[1];
    const float* weight = (const float*)d_in[2];
    const float* gamma  = (const float*)d_in[3];
    const float* beta   = (const float*)d_in[4];
    float* out = (float*)d_out;

    char*   ws      = (char*)d_ws;
    int*    grid    = (int*)(ws + OFF_GRID);
    short*  wfrag   = (short*)(ws + OFF_WFRAG);
    float*  stats   = (float*)(ws + OFF_STATS);
    u32*    cnt     = (u32*)(ws + OFF_CNT);
    u32*    cur     = (u32*)(ws + OFF_CUR);
    int*    sortidx = (int*)(ws + OFF_SIDX);
    int4*   csorted = (int4*)(ws + OFF_CSORT);
    ushort* fb16s   = (ushort*)(ws + OFF_FB16S);

    hipMemsetAsync(grid,  0xFF, SZ_GRID, stream);
    hipMemsetAsync(stats, 0, 512, stream);
    hipMemsetAsync(cnt,   0, NBKT*4, stream);
    hipMemsetAsync(fb16s + (size_t)BN_TOT*64, 0,
                   (size_t)(BN_PAD + 1 - BN_TOT)*128, stream);   // pads + ZROW

    k_count  <<<(BN_TOT + 255)/256, 256, 0, stream>>>(coords, grid, cnt);
    k_scan   <<<1, 1024, 0, stream>>>(cnt, cur);
    k_place  <<<(BN_PAD + 255)/256, 256, 0, stream>>>(feats, coords, cur,
                                                      sortidx, csorted, fb16s);
    k_prefrag<<<(27*4096)/256, 256, 0, stream>>>(weight, wfrag);
    k_conv   <<<CONV_BLOCKS, 256, 0, stream>>>(fb16s, csorted, grid, sortidx,
                                               (const ushort*)wfrag, out, stats);
    k_norm   <<<(BN_TOT*16)/256, 256, 0, stream>>>(out, stats, gamma, beta);
}

// Round 10
// 235.748 us; speedup vs baseline: 1.0534x; 1.0534x over previous
//
#include <hip/hip_runtime.h>

#define GS 128
#define GS3 (GS*GS*GS)
#define NPTS 150000
#define NBATCH 2
#define BN_TOT (NBATCH*NPTS)       // 300000
#define CONV_BLOCKS 1172           // 256 rows/block (4 waves x 64 rows)
#define BN_PAD (CONV_BLOCKS*256)   // 300032
#define ZROW   BN_PAD              // zero feature row index
#define EPS 1e-5f
#define NBKT 8192                  // 2 batches * 16^3 coarse buckets

// ws layout (~61 MB)
#define OFF_GRID   0ull
#define SZ_GRID    ((size_t)NBATCH*GS3*4)            // 16,777,216
#define OFF_WFRAG  (OFF_GRID + SZ_GRID)
#define SZ_WFRAG   ((size_t)27*4096*2)               // 221,184
#define OFF_STATS  (OFF_WFRAG + SZ_WFRAG)            // 512
#define OFF_CNT    (OFF_STATS + 512)                 // 32,768
#define OFF_CUR    (OFF_CNT + NBKT*4)                // 32,768
#define OFF_SIDX   (OFF_CUR + NBKT*4)                // 1,200,128
#define OFF_CSORT  (OFF_SIDX + 1200128)              // BN_PAD*16
#define OFF_FB16S  (OFF_CSORT + (size_t)BN_PAD*16)   // (BN_PAD+1)*128

typedef __attribute__((ext_vector_type(8)))  short bf16x8;
typedef __attribute__((ext_vector_type(16))) float f32x16;
typedef unsigned int u32;
typedef const __attribute__((address_space(1))) u32* gas_u32p;
typedef __attribute__((address_space(3))) u32* las_u32p;

__device__ __forceinline__ short f2bf(float f) {
    union { float f; unsigned u; } v; v.f = f;
    unsigned rr = v.u + 0x7fffu + ((v.u >> 16) & 1u);   // RNE
    return (short)(rr >> 16);
}

// ---------- kernel 1: grid scatter (max orig pid) + bucket histogram ----------
__global__ __launch_bounds__(256) void k_count(const int* __restrict__ coords,
                                               int* __restrict__ grid,
                                               u32* __restrict__ cnt) {
    int p = blockIdx.x*256 + threadIdx.x;
    if (p >= BN_TOT) return;
    int x = coords[p*3+0], y = coords[p*3+1], z = coords[p*3+2];
    int b = (p >= NPTS);
    atomicMax(&grid[(b<<21) | (x<<14) | (y<<7) | z], p);
    atomicAdd(&cnt[(b<<12) | ((x>>3)<<8) | ((y>>3)<<4) | (z>>3)], 1u);
}

// ---------- kernel 2: exclusive scan of 8192 bucket counts ----------
__global__ __launch_bounds__(1024) void k_scan(const u32* __restrict__ cnt,
                                               u32* __restrict__ cur) {
    __shared__ u32 ps[1024];
    int t = threadIdx.x;
    u32 l[8]; u32 s = 0;
    #pragma unroll
    for (int i = 0; i < 8; ++i) { l[i] = cnt[t*8+i]; s += l[i]; }
    ps[t] = s; __syncthreads();
    for (int off = 1; off < 1024; off <<= 1) {
        u32 v = (t >= off) ? ps[t-off] : 0u; __syncthreads();
        ps[t] += v; __syncthreads();
    }
    u32 run = (t == 0) ? 0u : ps[t-1];
    #pragma unroll
    for (int i = 0; i < 8; ++i) { cur[t*8+i] = run; run += l[i]; }
}

// ---------- kernel 3: place points in bucket order + bf16 features ----------
__global__ __launch_bounds__(256) void k_place(const float* __restrict__ feats,
                                               const int* __restrict__ coords,
                                               u32* __restrict__ cur,
                                               int* __restrict__ sortidx,
                                               int4* __restrict__ csorted,
                                               ushort* __restrict__ fb16s) {
    int p = blockIdx.x*256 + threadIdx.x;
    if (p >= BN_PAD) return;
    if (p >= BN_TOT) { csorted[p] = make_int4(-9,-9,-9,0); return; }
    int x = coords[p*3+0], y = coords[p*3+1], z = coords[p*3+2];
    int b = (p >= NPTS);
    int bkt = (b<<12) | ((x>>3)<<8) | ((y>>3)<<4) | (z>>3);
    int pos = (int)atomicAdd(&cur[bkt], 1u);
    sortidx[p] = pos;
    csorted[pos] = make_int4(x, y, z, p);
    const float4* s = (const float4*)(feats + (size_t)p*64);
    ushort* d = fb16s + (size_t)pos*64;
    #pragma unroll
    for (int i = 0; i < 8; ++i) {
        float4 a = s[2*i], c = s[2*i+1];
        ushort4 u0 = { (ushort)f2bf(a.x),(ushort)f2bf(a.y),(ushort)f2bf(a.z),(ushort)f2bf(a.w) };
        ushort4 u1 = { (ushort)f2bf(c.x),(ushort)f2bf(c.y),(ushort)f2bf(c.z),(ushort)f2bf(c.w) };
        ((ushort4*)d)[2*i] = u0; ((ushort4*)d)[2*i+1] = u1;
    }
}

// ---------- kernel 4: weight -> bf16 32x32x16 MFMA B-fragments ----------
// wfrag ushort idx ((((k*2+ct)*4 + kt)*64 + lane)*8 + i)
//   = W[k][ kt*16 + (lane>>5)*8 + i ][ ct*32 + (lane&31) ]
__global__ __launch_bounds__(256) void k_prefrag(const float* __restrict__ w,
                                                 short* __restrict__ wfrag) {
    int t = blockIdx.x * 256 + threadIdx.x;
    if (t >= 27*4096) return;
    int i    = t & 7;
    int lane = (t >> 3) & 63;
    int kt   = (t >> 9) & 3;
    int ct   = (t >> 11) & 1;
    int k    = t >> 12;
    int kk = kt*16 + (lane >> 5)*8 + i;
    int co = ct*32 + (lane & 31);
    wfrag[t] = f2bf(w[(k*64 + kk)*64 + co]);
}

// ---------- kernel 5: pipelined gathered MFMA conv (32x32x16 shape) ----------
// 4 waves/block, wave = 64 sorted rows (2x 32-row tiles) x 64 cout (2x 32).
// Inline 27x256 rulebook in LDS. Steady phase k: vmcnt(8) [drains A(k)x8 +
// S(k)x2, keeps A(k+1)x8 flying], ONE s_barrier, 8 ds_read_b128 B, stage(k+1)
// x2, 16 x mfma_32x32x16 (setprio), issue 8 A(k+2).
__global__ __launch_bounds__(256) void k_conv(
    const ushort* __restrict__ fb16s,
    const int4* __restrict__ csorted,
    const int* __restrict__ grid,
    const int* __restrict__ sortidx,
    const ushort* __restrict__ wfrag,
    float* __restrict__ out,
    float* __restrict__ gstats)
{
    __shared__ __align__(16) ushort bufs[2][4096];   // 2 x 8KB B double-buffer
    __shared__ int ids_lds[27*256];                  // 27.6KB block rulebook
    __shared__ float bsum[64], bsq[64];

    const int tid  = threadIdx.x;
    const int lane = tid & 63;
    const int wv   = tid >> 6;
    const int l31  = lane & 31;
    const int lh   = lane >> 5;                      // 0/1
    const int p0b  = blockIdx.x * 256;
    const int rb32 = wv*64 + l31;                    // + rt*32 per row-tile

    // ---- prologue A: inline rulebook (27 probes + sortidx per thread) ----
    {
        int4 c = csorted[p0b + tid];
        const bool pad = (p0b + tid >= BN_TOT);
        const int gb = (c.w >= NPTS) ? GS3 : 0;
        #pragma unroll
        for (int k = 0; k < 27; ++k) {
            int dx = k/9 - 1, dy = (k/3)%3 - 1, dz = k%3 - 1;   // compile-time
            int nx = c.x+dx, ny = c.y+dy, nz = c.z+dz;
            int ok = (int)(!pad & ((unsigned)nx < 128u) & ((unsigned)ny < 128u) &
                           ((unsigned)nz < 128u));
            int pid = grid[gb + ((nx&127)<<14) + ((ny&127)<<7) + (nz&127)];
            pid = ok ? pid : -1;
            int sv = sortidx[pid < 0 ? 0 : pid];
            ids_lds[k*256 + tid] = (pid >= 0) ? sv : ZROW;
        }
    }
    if (tid < 64) { bsum[tid] = 0.f; bsq[tid] = 0.f; }
    __syncthreads();                                 // rulebook ready, vmem drained

    auto stage = [&](int kk, int bsel) {             // 8KB slab, 2 instr/wave
        #pragma unroll
        for (int c = 0; c < 2; ++c) {
            int chunk = c*4 + wv;
            const u32* g = (const u32*)(wfrag + (size_t)kk*4096 + chunk*512) + lane*4;
            u32* l = (u32*)(&bufs[bsel][chunk*512]);
            __builtin_amdgcn_global_load_lds((gas_u32p)g, (las_u32p)l, 16, 0, 0);
        }
    };

// A-frag (32x32x16): lane covers row=l31 of tile rt, k = kt*16 + lh*8 + i
#define LDA8(AC, S) { _Pragma("unroll") for (int rt_ = 0; rt_ < 2; ++rt_) {   \
        const ushort* ap_ = fb16s + (size_t)(S)[rt_]*64 + lh*8;               \
        AC[rt_*4+0] = *(const bf16x8*)(ap_);                                  \
        AC[rt_*4+1] = *(const bf16x8*)(ap_ + 16);                             \
        AC[rt_*4+2] = *(const bf16x8*)(ap_ + 32);                             \
        AC[rt_*4+3] = *(const bf16x8*)(ap_ + 48); } }
#define LDIDS(S, kk) { S[0] = ids_lds[(kk)*256 + rb32];                       \
                       S[1] = ids_lds[(kk)*256 + rb32 + 32]; }

    f32x16 acc[2][2];
    #pragma unroll
    for (int rt = 0; rt < 2; ++rt)
        #pragma unroll
        for (int ct = 0; ct < 2; ++ct) acc[rt][ct] = (f32x16)(0.f);

    bf16x8 aE[8], aO[8];
    int sE[2], sO[2];

    // ---- prologue B: fill pipeline ----
    LDIDS(sE, 0); LDIDS(sO, 1);
    __builtin_amdgcn_sched_barrier(0);
    LDA8(aE, sE);                                    // A(0) x8
    __builtin_amdgcn_sched_barrier(0);
    stage(0, 0);                                     // S(0) x2
    __builtin_amdgcn_sched_barrier(0);
    LDA8(aO, sO);                                    // A(1) x8
    __builtin_amdgcn_sched_barrier(0);
    // invariant entering phase k: outstanding = [A(k)x8, S(k)x2, A(k+1)x8]

    auto phase = [&](int k, bf16x8 (&AC)[8]) {
        asm volatile("s_waitcnt vmcnt(8)" ::: "memory");
        __builtin_amdgcn_sched_barrier(0);
        __builtin_amdgcn_s_barrier();
        __builtin_amdgcn_sched_barrier(0);
        const ushort* bb = bufs[k & 1];
        bf16x8 B[8];                                 // [ct*4 + kt]
        #pragma unroll
        for (int f = 0; f < 8; ++f)
            B[f] = *(const bf16x8*)(bb + f*512 + lane*8);
        int kp2 = (k+2 > 26) ? 26 : k+2;
        int sn[2]; LDIDS(sn, kp2);
        if (k < 26) stage(k+1, (k+1) & 1);
        __builtin_amdgcn_sched_barrier(0);
        __builtin_amdgcn_s_setprio(1);
        #pragma unroll
        for (int kt = 0; kt < 4; ++kt) {
            acc[0][0] = __builtin_amdgcn_mfma_f32_32x32x16_bf16(AC[kt],   B[kt],   acc[0][0], 0,0,0);
            acc[0][1] = __builtin_amdgcn_mfma_f32_32x32x16_bf16(AC[kt],   B[4+kt], acc[0][1], 0,0,0);
            acc[1][0] = __builtin_amdgcn_mfma_f32_32x32x16_bf16(AC[4+kt], B[kt],   acc[1][0], 0,0,0);
            acc[1][1] = __builtin_amdgcn_mfma_f32_32x32x16_bf16(AC[4+kt], B[4+kt], acc[1][1], 0,0,0);
        }
        __builtin_amdgcn_s_setprio(0);
        __builtin_amdgcn_sched_barrier(0);
        LDA8(AC, sn);                                // A(k+2) into freed regs
        __builtin_amdgcn_sched_barrier(0);
    };

    #pragma unroll 1
    for (int t = 0; t < 13; ++t) {
        phase(2*t,   aE);
        phase(2*t+1, aO);
    }
    phase(26, aE);

    // ---- epilogue: scatter to out[orig pid] ----
    // C/D (verified m74/m101): col = ct*32 + l31, row = (reg&3)+8*(reg>>2)+4*lh
    #pragma unroll
    for (int rt = 0; rt < 2; ++rt) {
        #pragma unroll
        for (int g = 0; g < 4; ++g) {                // reg>>2
            #pragma unroll
            for (int q = 0; q < 4; ++q) {            // reg&3
                int row = p0b + wv*64 + rt*32 + q + 8*g + 4*lh;
                if (row < BN_TOT) {
                    int opid = csorted[row].w;
                    float* ob = out + (size_t)opid*64 + l31;
                    ob[ 0] = acc[rt][0][g*4+q];
                    ob[32] = acc[rt][1][g*4+q];
                }
            }
        }
    }

    // ---- fused stats (pad rows contribute exact zeros) ----
    float s0 = 0.f, q0 = 0.f, s1 = 0.f, q1 = 0.f;
    #pragma unroll
    for (int rt = 0; rt < 2; ++rt)
        #pragma unroll
        for (int e = 0; e < 16; ++e) {
            float v0 = acc[rt][0][e]; s0 += v0; q0 += v0*v0;
            float v1 = acc[rt][1][e]; s1 += v1; q1 += v1*v1;
        }
    atomicAdd(&bsum[l31],      s0);  atomicAdd(&bsq[l31],      q0);
    atomicAdd(&bsum[32 + l31], s1);  atomicAdd(&bsq[32 + l31], q1);
    __syncthreads();
    if (tid < 64) { atomicAdd(&gstats[tid], bsum[tid]); atomicAdd(&gstats[64+tid], bsq[tid]); }
#undef LDA8
#undef LDIDS
}

// ---------- kernel 6: normalize + affine + ReLU, in place ----------
__global__ __launch_bounds__(256) void k_norm(float* __restrict__ out,
                                              const float* __restrict__ stats,
                                              const float* __restrict__ gamma,
                                              const float* __restrict__ beta) {
    int i = blockIdx.x*256 + threadIdx.x;
    const int n4 = BN_TOT*16;
    if (i >= n4) return;
    float4 v = ((const float4*)out)[i];
    int ch = (i & 15) * 4;
    float o[4] = {v.x, v.y, v.z, v.w};
    float rp[4];
    #pragma unroll
    for (int j = 0; j < 4; ++j) {
        int c = ch + j;
        float mean = stats[c] * (1.f/BN_TOT);
        float var  = stats[64+c] * (1.f/BN_TOT) - mean*mean;
        float y = (o[j] - mean) * rsqrtf(var + EPS) * gamma[c] + beta[c];
        rp[j] = fmaxf(y, 0.f);
    }
    float4 rv; rv.x = rp[0]; rv.y = rp[1]; rv.z = rp[2]; rv.w = rp[3];
    ((float4*)out)[i] = rv;
}

extern "C" void kernel_launch(void* const* d_in, const int* in_sizes, int n_in,
                              void* d_out, int out_size, void* d_ws, size_t ws_size,
                              hipStream_t stream) {
    const float* feats  = (const float*)d_in[0];
    const int*   coords = (const int*)d_in[1];
    const float* weight = (const float*)d_in[2];
    const float* gamma  = (const float*)d_in[3];
    const float* beta   = (const float*)d_in[4];
    float* out = (float*)d_out;

    char*   ws      = (char*)d_ws;
    int*    grid    = (int*)(ws + OFF_GRID);
    short*  wfrag   = (short*)(ws + OFF_WFRAG);
    float*  stats   = (float*)(ws + OFF_STATS);
    u32*    cnt     = (u32*)(ws + OFF_CNT);
    u32*    cur     = (u32*)(ws + OFF_CUR);
    int*    sortidx = (int*)(ws + OFF_SIDX);
    int4*   csorted = (int4*)(ws + OFF_CSORT);
    ushort* fb16s   = (ushort*)(ws + OFF_FB16S);

    hipMemsetAsync(grid,  0xFF, SZ_GRID, stream);
    hipMemsetAsync(stats, 0, 512, stream);
    hipMemsetAsync(cnt,   0, NBKT*4, stream);
    hipMemsetAsync(fb16s + (size_t)BN_TOT*64, 0,
                   (size_t)(BN_PAD + 1 - BN_TOT)*128, stream);   // pads + ZROW

    k_count  <<<(BN_TOT + 255)/256, 256, 0, stream>>>(coords, grid, cnt);
    k_scan   <<<1, 1024, 0, stream>>>(cnt, cur);
    k_place  <<<(BN_PAD + 255)/256, 256, 0, stream>>>(feats, coords, cur,
                                                      sortidx, csorted, fb16s);
    k_prefrag<<<(27*4096)/256, 256, 0, stream>>>(weight, wfrag);
    k_conv   <<<CONV_BLOCKS, 256, 0, stream>>>(fb16s, csorted, grid, sortidx,
                                               (const ushort*)wfrag, out, stats);
    k_norm   <<<(BN_TOT*16)/256, 256, 0, stream>>>(out, stats, gamma, beta);
}